// Round 13
// baseline (705.825 us; speedup 1.0000x reference)
//
#include <hip/hip_runtime.h>
#include <math.h>

typedef __attribute__((ext_vector_type(8))) short bf16x8;
typedef __attribute__((ext_vector_type(4))) float f32x4;
typedef unsigned short u16;

__device__ __forceinline__ short f2bf(float x) {
  union { float f; unsigned u; } c; c.f = x;
  unsigned u = c.u;
  u += 0x7fffu + ((u >> 16) & 1u);
  return (short)(u >> 16);
}
__device__ __forceinline__ float bf2f(u16 b) {
  union { unsigned u; float f; } c; c.u = ((unsigned)b) << 16; return c.f;
}
__device__ __forceinline__ unsigned pack2(float a, float b) {
  return ((unsigned)(u16)f2bf(a)) | (((unsigned)(u16)f2bf(b)) << 16);
}
__device__ __forceinline__ unsigned cvtpk(float lo, float hi) {
  unsigned r;
  asm("v_cvt_pk_bf16_f32 %0, %1, %2" : "=v"(r) : "v"(lo), "v"(hi));
  return r;
}
__device__ __forceinline__ float fast_erf(float x) {
  float ax = fabsf(x);
  float t = __frcp_rn(1.f + 0.3275911f * ax);
  float p = ((((1.061405429f * t - 1.453152027f) * t) + 1.421413741f) * t - 0.284496736f) * t + 0.254829592f;
  float y = 1.f - p * t * __expf(-ax * ax);
  return copysignf(y, x);
}
__device__ __forceinline__ void gload16(const void* g, void* l) {
  __builtin_amdgcn_global_load_lds(
      (const __attribute__((address_space(1))) void*)g,
      (__attribute__((address_space(3))) void*)l, 16, 0, 0);
}

// ---------------- index handling ----------------
__global__ void detect_kernel(const unsigned* __restrict__ idx32, int* __restrict__ flag) {
  __shared__ int anyNZ;
  if (threadIdx.x == 0) anyNZ = 0;
  __syncthreads();
  unsigned v = idx32[threadIdx.x * 2 + 1];
  if (v != 0u) atomicOr(&anyNZ, 1);
  __syncthreads();
  if (threadIdx.x == 0) *flag = (anyNZ == 0) ? 1 : 0;  // 1 => int64 input
}

// convert idx to int32 AND count src occurrences (cnt pre-zeroed)
__global__ void convert_count_kernel(const void* __restrict__ in, int* __restrict__ s32,
                                     const int* __restrict__ flag, int* __restrict__ cnt,
                                     int E) {
  int i = blockIdx.x * 256 + threadIdx.x;
  if (i >= 2 * E) return;
  int f = *flag;
  int v = f ? (int)((const long long*)in)[i] : ((const int*)in)[i];
  s32[i] = v;
  if (i < E) atomicAdd(&cnt[v], 1);
}

__global__ void __launch_bounds__(1024)
scan_kernel(const int* __restrict__ cnt, int* __restrict__ offs, int n) {
  __shared__ int sp[1024];
  int t = threadIdx.x;
  int chunk = (n + 1023) / 1024;
  int begin = t * chunk;
  int end = begin + chunk; if (end > n) end = n; if (begin > n) begin = n;
  int s = 0;
  for (int i = begin; i < end; ++i) s += cnt[i];
  sp[t] = s;
  __syncthreads();
  for (int o = 1; o < 1024; o <<= 1) {
    int v = (t >= o) ? sp[t - o] : 0;
    __syncthreads();
    sp[t] += v;
    __syncthreads();
  }
  int run = (t == 0) ? 0 : sp[t - 1];
  for (int i = begin; i < end; ++i) { offs[i] = run; run += cnt[i]; }
  if (t == 0) offs[n] = sp[1023];
}

// order[p] = original edge index at CSR position p
__global__ void scatter_kernel(const int* __restrict__ src, const int* __restrict__ offs,
                               int* __restrict__ cur, int* __restrict__ order, int E) {
  int i = blockIdx.x * 256 + threadIdx.x;
  if (i >= E) return;
  int s = src[i];
  int p = offs[s] + atomicAdd(&cur[s], 1);
  order[p] = i;
}

// ---------------- weight fp32 -> bf16 ----------------
// layout: W1[49152] | W2[16384] | W3[512] | Wv[16384] | Wo[16384] | Wg[16384]
// W1/W2/Wv are CHUNK-SWIZZLED: chunk c (32 K-cols) stored at
//   chunkBase + row*32 + ((s ^ ((row>>1)&3))<<3) + e   (s = (k%32)/8, e = k%8)
__global__ void wcvt_kernel(const float* __restrict__ B1, const float* __restrict__ B2,
                            const float* __restrict__ B3, const float* __restrict__ Wv,
                            const float* __restrict__ Wo, const float* __restrict__ Wg,
                            short* __restrict__ o) {
  int i = blockIdx.x * 256 + threadIdx.x;
  if (i >= 115200) return;
  float val; int dst;
  if (i < 49152) {
    int row = i / 384, k = i % 384;
    val = B1[i];
    int c = k >> 5, s = (k >> 3) & 3, e = k & 7;
    dst = c * 4096 + row * 32 + ((s ^ ((row >> 1) & 3)) << 3) + e;
  } else if (i < 65536) {
    int j = i - 49152; int row = j >> 7, k = j & 127;
    val = B2[j];
    int c = k >> 5, s = (k >> 3) & 3, e = k & 7;
    dst = 49152 + c * 4096 + row * 32 + ((s ^ ((row >> 1) & 3)) << 3) + e;
  } else if (i < 66048) { val = B3[i - 65536]; dst = i; }
  else if (i < 82432) {
    int j = i - 66048; int row = j >> 7, k = j & 127;
    val = Wv[j];
    int c = k >> 5, s = (k >> 3) & 3, e = k & 7;
    dst = 66048 + c * 4096 + row * 32 + ((s ^ ((row >> 1) & 3)) << 3) + e;
  }
  else if (i < 98816)  { val = Wo[i - 82432]; dst = i; }
  else                 { val = Wg[i - 98816]; dst = i; }
  o[dst] = f2bf(val);
}

// ---------------- fp32 -> bf16 bulk convert (hV only, 5 MB) ----------------
__global__ void cvtbf_kernel(const float* __restrict__ in, u16* __restrict__ out, long n8) {
  long i = (long)blockIdx.x * blockDim.x + threadIdx.x;
  long stride = (long)gridDim.x * blockDim.x;
  for (; i < n8; i += stride) {
    long b = i * 8;
    float4 a = *(const float4*)(in + b);
    float4 c = *(const float4*)(in + b + 4);
    uint4 u;
    u.x = pack2(a.x, a.y); u.y = pack2(a.z, a.w);
    u.z = pack2(c.x, c.y); u.w = pack2(c.z, c.w);
    *(uint4*)(out + b) = u;
  }
}

// ---------------- K1: logits kernel — W1+W2 RESIDENT in LDS ----------------
// 512 threads = 8 waves (2 row-groups x 4 col-groups, 32x32 wave tiles).
// Weights staged ONCE per block; each block grid-strides over 64-edge tiles.
// The 12 L1 + 4 L2 MFMA steps have NO barriers (weights are read-only LDS).
__global__ void __launch_bounds__(512, 1)
logits_kernel(const u16* __restrict__ hVb, const float* __restrict__ hE,
              const int* __restrict__ src, const int* __restrict__ dst,
              const short* __restrict__ W1, const float* __restrict__ b1,
              const short* __restrict__ W2, const float* __restrict__ b2,
              const short* __restrict__ W3b, const float* __restrict__ b3,
              float* __restrict__ logits, int E, int nTiles) {
  __shared__ u16 sW1[49152];          // 96KB resident
  __shared__ u16 sW2[16384];          // 32KB resident
  __shared__ u16 sEH[8192];           // 16KB: hE tile, then H tile
  __shared__ float sPart[64][4][4];   // 4KB

  const int t = threadIdx.x;
  const int lane = t & 63;
  const int wid = t >> 6;
  const int wrow = (wid >> 2) * 32;
  const int wcol = (wid & 3) * 32;
  const int lrow = lane & 15;
  const int kgrp = lane >> 4;

  // ---- one-time: stage W1 + W2 (pre-swizzled, linear copy) ----
#pragma unroll
  for (int i = 0; i < 12; ++i) {
    int L = t + i * 512;
    gload16(W1 + L * 8, &sW1[L * 8]);
  }
#pragma unroll
  for (int i = 0; i < 4; ++i) {
    int L = t + i * 512;
    gload16(W2 + L * 8, &sW2[L * 8]);
  }
  float b1c[2], b2c[2], w3v[4][2];
#pragma unroll
  for (int nf = 0; nf < 2; ++nf) {
    int col = wcol + nf * 16 + lrow;
    b1c[nf] = b1[col]; b2c[nf] = b2[col];
#pragma unroll
    for (int h = 0; h < 4; ++h) w3v[h][nf] = bf2f((u16)W3b[h * 128 + col]);
  }
  const float b3c0 = b3[0], b3c1 = b3[1], b3c2 = b3[2], b3c3 = b3[3];
  asm volatile("s_waitcnt vmcnt(0)" ::: "memory");
  __syncthreads();

  f32x4 acc[2][2];
  auto ZACC = [&]() {
#pragma unroll
    for (int mi = 0; mi < 2; ++mi)
#pragma unroll
      for (int nf = 0; nf < 2; ++nf)
#pragma unroll
        for (int q = 0; q < 4; ++q) acc[mi][nf][q] = 0.f;
  };
  auto LDSA = [&](int kk, bf16x8* a) {
#pragma unroll
    for (int mi = 0; mi < 2; ++mi) {
      int row = wrow + mi * 16 + lrow;
      int seg = (kk >> 3) ^ (row & 15);
      a[mi] = *(const bf16x8*)&sEH[row * 128 + seg * 8];
    }
  };

  for (int tile = blockIdx.x; tile < nTiles; tile += gridDim.x) {
    const int eBase = tile * 64;
    // stage hE (fp32 contiguous) -> sEH bf16, swizzled
#pragma unroll
    for (int i = 0; i < 2; ++i) {
      int u = t + i * 512;
      int row = u >> 4, sg = u & 15;
      const float* p = hE + (size_t)min(eBase + row, E - 1) * 128 + sg * 8;
      float4 f0 = *(const float4*)p;
      float4 f1 = *(const float4*)(p + 4);
      uint4 cv;
      cv.x = cvtpk(f0.x, f0.y); cv.y = cvtpk(f0.z, f0.w);
      cv.z = cvtpk(f1.x, f1.y); cv.w = cvtpk(f1.z, f1.w);
      *(uint4*)&sEH[row * 128 + ((sg ^ (row & 15)) * 8)] = cv;
    }
    // hoist hV gathers (L2/L3-resident)
    bf16x8 aS[4][2], aD[4][2];
    {
      int rS[2], rD[2];
#pragma unroll
      for (int mi = 0; mi < 2; ++mi) {
        int e = min(eBase + wrow + mi * 16 + lrow, E - 1);
        rS[mi] = src[e]; rD[mi] = dst[e];
      }
#pragma unroll
      for (int c4 = 0; c4 < 4; ++c4) {
        int kk = c4 * 32 + kgrp * 8;
#pragma unroll
        for (int mi = 0; mi < 2; ++mi) {
          aS[c4][mi] = *(const bf16x8*)(hVb + (size_t)rS[mi] * 128 + kk);
          aD[c4][mi] = *(const bf16x8*)(hVb + (size_t)rD[mi] * 128 + kk);
        }
      }
    }
    __syncthreads();

    // ---- layer 1: 12 chunks, NO barriers ----
    ZACC();
#pragma unroll
    for (int c = 0; c < 12; ++c) {
      bf16x8 a[2], b[2];
      if (c < 4)      { a[0] = aS[c][0]; a[1] = aS[c][1]; }
      else if (c < 8) { LDSA((c - 4) * 32 + kgrp * 8, a); }
      else            { a[0] = aD[c - 8][0]; a[1] = aD[c - 8][1]; }
#pragma unroll
      for (int nf = 0; nf < 2; ++nf) {
        int row_ = wcol + nf * 16 + lrow;
        b[nf] = *(const bf16x8*)&sW1[c * 4096 + row_ * 32 + ((kgrp ^ ((row_ >> 1) & 3)) << 3)];
      }
#pragma unroll
      for (int nf = 0; nf < 2; ++nf)
#pragma unroll
        for (int mi = 0; mi < 2; ++mi)
          acc[mi][nf] = __builtin_amdgcn_mfma_f32_16x16x32_bf16(a[mi], b[nf], acc[mi][nf], 0, 0, 0);
    }
    __syncthreads();   // all sEH reads complete

    // ---- H = relu(acc + b1) -> sEH (same buffer) ----
#pragma unroll
    for (int mi = 0; mi < 2; ++mi)
#pragma unroll
      for (int nf = 0; nf < 2; ++nf)
#pragma unroll
        for (int q = 0; q < 4; ++q) {
          int row = wrow + mi * 16 + kgrp * 4 + q;
          int col = wcol + nf * 16 + lrow;
          int seg = (col >> 3) ^ (row & 15);
          sEH[row * 128 + seg * 8 + (col & 7)] =
              (u16)f2bf(fmaxf(acc[mi][nf][q] + b1c[nf], 0.f));
        }
    __syncthreads();

    // ---- layer 2: 4 chunks from resident sW2 ----
    ZACC();
#pragma unroll
    for (int c = 0; c < 4; ++c) {
      bf16x8 a[2], b[2];
      LDSA(c * 32 + kgrp * 8, a);
#pragma unroll
      for (int nf = 0; nf < 2; ++nf) {
        int row_ = wcol + nf * 16 + lrow;
        b[nf] = *(const bf16x8*)&sW2[c * 4096 + row_ * 32 + ((kgrp ^ ((row_ >> 1) & 3)) << 3)];
      }
#pragma unroll
      for (int nf = 0; nf < 2; ++nf)
#pragma unroll
        for (int mi = 0; mi < 2; ++mi)
          acc[mi][nf] = __builtin_amdgcn_mfma_f32_16x16x32_bf16(a[mi], b[nf], acc[mi][nf], 0, 0, 0);
    }

    // ---- folded layer 3 -> sPart[row][h][colgroup] ----
#pragma unroll
    for (int mi = 0; mi < 2; ++mi)
#pragma unroll
      for (int q = 0; q < 4; ++q) {
        float p0 = 0.f, p1 = 0.f, p2 = 0.f, p3 = 0.f;
#pragma unroll
        for (int nf = 0; nf < 2; ++nf) {
          float x = fmaxf(acc[mi][nf][q] + b2c[nf], 0.f);
          p0 += x * w3v[0][nf]; p1 += x * w3v[1][nf];
          p2 += x * w3v[2][nf]; p3 += x * w3v[3][nf];
        }
#pragma unroll
        for (int o = 1; o < 16; o <<= 1) {
          p0 += __shfl_xor(p0, o); p1 += __shfl_xor(p1, o);
          p2 += __shfl_xor(p2, o); p3 += __shfl_xor(p3, o);
        }
        if (lrow < 4) {
          float pw = (lrow == 0) ? p0 : (lrow == 1) ? p1 : (lrow == 2) ? p2 : p3;
          sPart[wrow + mi * 16 + kgrp * 4 + q][lrow][wid & 3] = pw;
        }
      }
    __syncthreads();
    if (t < 256) {
      int r = t >> 2, h = t & 3;
      float bb = (h == 0) ? b3c0 : (h == 1) ? b3c1 : (h == 2) ? b3c2 : b3c3;
      float lg = (sPart[r][h][0] + sPart[r][h][1] + sPart[r][h][2] + sPart[r][h][3] + bb)
                 * 0.17677669529663687f;
      int e = eBase + r;
      if (e < E) logits[(size_t)e * 4 + h] = lg;
    }
    __syncthreads();   // sPart + sEH safe for next tile
  }
}

// ---------------- K2: V projection — Wv RESIDENT, streaming GEMM ----------
__global__ void __launch_bounds__(512, 3)
vproj_kernel(const float* __restrict__ hE, const short* __restrict__ Wv,
             const float* __restrict__ bv, u16* __restrict__ Vout,
             int E, int nTiles) {
  __shared__ u16 sWv[16384];   // 32KB resident
  __shared__ u16 sE[8192];     // 16KB tile buffer (also gelu bounce)

  const int t = threadIdx.x;
  const int lane = t & 63;
  const int wid = t >> 6;
  const int wrow = (wid >> 2) * 32;
  const int wcol = (wid & 3) * 32;
  const int lrow = lane & 15;
  const int kgrp = lane >> 4;

#pragma unroll
  for (int i = 0; i < 4; ++i) {
    int L = t + i * 512;
    gload16(Wv + L * 8, &sWv[L * 8]);
  }
  float bvc[2];
#pragma unroll
  for (int nf = 0; nf < 2; ++nf) bvc[nf] = bv[wcol + nf * 16 + lrow];
  asm volatile("s_waitcnt vmcnt(0)" ::: "memory");
  __syncthreads();

  f32x4 acc[2][2];
  for (int tile = blockIdx.x; tile < nTiles; tile += gridDim.x) {
    const int eBase = tile * 64;
#pragma unroll
    for (int i = 0; i < 2; ++i) {
      int u = t + i * 512;
      int row = u >> 4, sg = u & 15;
      const float* p = hE + (size_t)min(eBase + row, E - 1) * 128 + sg * 8;
      float4 f0 = *(const float4*)p;
      float4 f1 = *(const float4*)(p + 4);
      uint4 cv;
      cv.x = cvtpk(f0.x, f0.y); cv.y = cvtpk(f0.z, f0.w);
      cv.z = cvtpk(f1.x, f1.y); cv.w = cvtpk(f1.z, f1.w);
      *(uint4*)&sE[row * 128 + ((sg ^ (row & 15)) * 8)] = cv;
    }
    __syncthreads();

#pragma unroll
    for (int mi = 0; mi < 2; ++mi)
#pragma unroll
      for (int nf = 0; nf < 2; ++nf)
#pragma unroll
        for (int q = 0; q < 4; ++q) acc[mi][nf][q] = 0.f;
#pragma unroll
    for (int c = 0; c < 4; ++c) {
      bf16x8 a[2], b[2];
#pragma unroll
      for (int mi = 0; mi < 2; ++mi) {
        int row = wrow + mi * 16 + lrow;
        int seg = ((c * 32 + kgrp * 8) >> 3) ^ (row & 15);
        a[mi] = *(const bf16x8*)&sE[row * 128 + seg * 8];
      }
#pragma unroll
      for (int nf = 0; nf < 2; ++nf) {
        int row_ = wcol + nf * 16 + lrow;
        b[nf] = *(const bf16x8*)&sWv[c * 4096 + row_ * 32 + ((kgrp ^ ((row_ >> 1) & 3)) << 3)];
      }
#pragma unroll
      for (int nf = 0; nf < 2; ++nf)
#pragma unroll
        for (int mi = 0; mi < 2; ++mi)
          acc[mi][nf] = __builtin_amdgcn_mfma_f32_16x16x32_bf16(a[mi], b[nf], acc[mi][nf], 0, 0, 0);
    }
    __syncthreads();   // all sE reads done

    // gelu -> sE (bounce), then coalesced store
#pragma unroll
    for (int mi = 0; mi < 2; ++mi)
#pragma unroll
      for (int nf = 0; nf < 2; ++nf)
#pragma unroll
        for (int q = 0; q < 4; ++q) {
          int row = wrow + mi * 16 + kgrp * 4 + q;
          int col = wcol + nf * 16 + lrow;
          float x = acc[mi][nf][q] + bvc[nf];
          float g = 0.5f * x * (1.0f + fast_erf(x * 0.70710678118654752f));
          int seg = (col >> 3) ^ (row & 15);
          sE[row * 128 + seg * 8 + (col & 7)] = (u16)f2bf(g);
        }
    __syncthreads();
#pragma unroll
    for (int i = 0; i < 2; ++i) {
      int u = t + i * 512;
      int row = u >> 4, g16 = u & 15;
      int seg = g16 ^ (row & 15);
      uint4 v = *(const uint4*)&sE[row * 128 + seg * 8];
      int e = eBase + row;
      if (e < E) *(uint4*)(Vout + (size_t)e * 128 + g16 * 8) = v;
    }
    __syncthreads();   // sE safe for next tile
  }
}

// ---------------- node kernels (order-indirected) ----------------
__global__ void __launch_bounds__(256)
nm_kernel(const float* __restrict__ logits, const int* __restrict__ offs,
          const int* __restrict__ order, float* __restrict__ attw,
          float* __restrict__ inv, int nN) {
  const int wid = threadIdx.x >> 6, lane = threadIdx.x & 63;
  const int nW = gridDim.x * 4;
  for (int v = blockIdx.x * 4 + wid; v < nN; v += nW) {
    const int base = offs[v];
    const int deg = offs[v + 1] - base;
    float m0 = -3e38f, m1 = -3e38f, m2 = -3e38f, m3 = -3e38f;
    for (int i = lane; i < deg; i += 64) {
      int e = order[base + i];
      float4 l = *(const float4*)(logits + (size_t)e * 4);
      m0 = fmaxf(m0, l.x); m1 = fmaxf(m1, l.y);
      m2 = fmaxf(m2, l.z); m3 = fmaxf(m3, l.w);
    }
#pragma unroll
    for (int o = 32; o > 0; o >>= 1) {
      m0 = fmaxf(m0, __shfl_xor(m0, o)); m1 = fmaxf(m1, __shfl_xor(m1, o));
      m2 = fmaxf(m2, __shfl_xor(m2, o)); m3 = fmaxf(m3, __shfl_xor(m3, o));
    }
    float d0 = 0.f, d1 = 0.f, d2 = 0.f, d3 = 0.f;
    for (int i = lane; i < deg; i += 64) {
      int e = order[base + i];
      float4 l = *(const float4*)(logits + (size_t)e * 4);
      float4 ex;
      ex.x = __expf(l.x - m0); ex.y = __expf(l.y - m1);
      ex.z = __expf(l.z - m2); ex.w = __expf(l.w - m3);
      *(float4*)(attw + (size_t)e * 4) = ex;
      d0 += ex.x; d1 += ex.y; d2 += ex.z; d3 += ex.w;
    }
#pragma unroll
    for (int o = 32; o > 0; o >>= 1) {
      d0 += __shfl_xor(d0, o); d1 += __shfl_xor(d1, o);
      d2 += __shfl_xor(d2, o); d3 += __shfl_xor(d3, o);
    }
    if (lane < 4) {
      float dv = (lane == 0) ? d0 : (lane == 1) ? d1 : (lane == 2) ? d2 : d3;
      inv[(size_t)v * 4 + lane] = (dv > 0.f) ? 1.f / dv : 0.f;
    }
  }
}

__device__ __forceinline__ float dot8(const float* ag, uint4 w) {
  unsigned wr[4] = {w.x, w.y, w.z, w.w};
  float s = 0.f;
#pragma unroll
  for (int q = 0; q < 4; ++q) {
    s += ag[2 * q]     * bf2f((u16)(wr[q] & 0xffffu));
    s += ag[2 * q + 1] * bf2f((u16)(wr[q] >> 16));
  }
  return s;
}

// one node per WAVE; lane = 16 dim-groups x 4 edge-slots (16B V loads);
// Wo/Wg cached in LDS (XOR-swizzled); grid-stride over nodes.
__global__ void __launch_bounds__(256, 2)
agg_kernel(const float* __restrict__ hV, const float* __restrict__ attw,
           const float* __restrict__ inv, const u16* __restrict__ V,
           const int* __restrict__ offs, const int* __restrict__ order,
           const short* __restrict__ Wob, const short* __restrict__ Wgb,
           const float* __restrict__ gb, float* __restrict__ out, int nN) {
  __shared__ u16 sW[2][16384];      // 64KB
  __shared__ float sAgg[4][132];
  const int t = threadIdx.x;
#pragma unroll
  for (int i = 0; i < 8; ++i) {
    int idx = t + i * 256;          // 0..2047 uint4 per matrix
    int row = idx >> 4, k16 = idx & 15;
    int di = row * 128 + ((k16 ^ (row & 15)) * 8);
    *(uint4*)&sW[0][di] = ((const uint4*)Wob)[idx];
    *(uint4*)&sW[1][di] = ((const uint4*)Wgb)[idx];
  }
  __syncthreads();
  const int wid = t >> 6, lane = t & 63;
  const int dgrp = lane & 15, egrp = lane >> 4, h = dgrp >> 2;
  const int j0 = lane, j1 = lane + 64;
  const int s0 = (j0 & 15), s1 = (j1 & 15);
  for (int v = blockIdx.x * 4 + wid; v < nN; v += gridDim.x * 4) {
    const int base = offs[v], deg = offs[v + 1] - base;
    float a[8];
#pragma unroll
    for (int q = 0; q < 8; ++q) a[q] = 0.f;
    for (int i = egrp; i < deg; i += 4) {
      int e = order[base + i];
      float w = attw[(size_t)e * 4 + h];
      bf16x8 vv = *(const bf16x8*)(V + (size_t)e * 128 + dgrp * 8);
#pragma unroll
      for (int q = 0; q < 8; ++q) a[q] += w * bf2f((u16)vv[q]);
    }
#pragma unroll
    for (int q = 0; q < 8; ++q) {
      a[q] += __shfl_xor(a[q], 16);
      a[q] += __shfl_xor(a[q], 32);
    }
    if (egrp == 0) {
      float innv = inv[(size_t)v * 4 + h];
#pragma unroll
      for (int q = 0; q < 8; ++q) sAgg[wid][dgrp * 8 + q] = a[q] * innv;
    }
    asm volatile("s_waitcnt lgkmcnt(0)" ::: "memory");
    __builtin_amdgcn_wave_barrier();
    float o0 = 0.f, o1 = 0.f, g0 = 0.f, g1 = 0.f;
#pragma unroll 4
    for (int k = 0; k < 128; k += 8) {
      float a8[8];
#pragma unroll
      for (int q = 0; q < 8; ++q) a8[q] = sAgg[wid][k + q];
      int k16 = k >> 3;
      uint4 wo0 = *(const uint4*)&sW[0][j0 * 128 + ((k16 ^ s0) * 8)];
      uint4 wo1 = *(const uint4*)&sW[0][j1 * 128 + ((k16 ^ s1) * 8)];
      uint4 wg0 = *(const uint4*)&sW[1][j0 * 128 + ((k16 ^ s0) * 8)];
      uint4 wg1 = *(const uint4*)&sW[1][j1 * 128 + ((k16 ^ s1) * 8)];
      o0 += dot8(a8, wo0); o1 += dot8(a8, wo1);
      g0 += dot8(a8, wg0); g1 += dot8(a8, wg1);
    }
    float gg0 = 1.f / (1.f + __expf(-(g0 + gb[j0])));
    float gg1 = 1.f / (1.f + __expf(-(g1 + gb[j1])));
    out[(size_t)v * 128 + j0] = hV[(size_t)v * 128 + j0] + o0 * gg0;
    out[(size_t)v * 128 + j1] = hV[(size_t)v * 128 + j1] + o1 * gg1;
    asm volatile("s_waitcnt lgkmcnt(0)" ::: "memory");
    __builtin_amdgcn_wave_barrier();
  }
}

// ---------------- fallback (ws too small marker) ----------------
__global__ void fb_kernel(const float* __restrict__ hV, float* __restrict__ out, int n) {
  int i = blockIdx.x * 256 + threadIdx.x;
  if (i < n) out[i] = hV[i] + 0.5f;
}

extern "C" void kernel_launch(void* const* d_in, const int* in_sizes, int n_in,
                              void* d_out, int out_size, void* d_ws, size_t ws_size,
                              hipStream_t stream) {
  const float* hV   = (const float*)d_in[0];
  const float* hE   = (const float*)d_in[1];
  const void*  eidx = d_in[2];
  const float* WvW  = (const float*)d_in[3];
  const float* WvB  = (const float*)d_in[4];
  const float* B1w  = (const float*)d_in[5];
  const float* B1b  = (const float*)d_in[6];
  const float* B2w  = (const float*)d_in[7];
  const float* B2b  = (const float*)d_in[8];
  const float* B3w  = (const float*)d_in[9];
  const float* B3b  = (const float*)d_in[10];
  const float* WoW  = (const float*)d_in[11];
  const float* GW   = (const float*)d_in[12];
  const float* GB   = (const float*)d_in[13];

  const int Nn = in_sizes[0] / 128;
  const int E  = in_sizes[1] / 128;
  if (Nn <= 0 || E <= 0) return;

  char* ws = (char*)d_ws;
  size_t off = 0;
  auto alloc = [&](size_t b) { size_t o = off; off += (b + 255) & ~(size_t)255; return o; };
  const size_t o_idx   = alloc((size_t)2 * E * 4);
  const size_t o_cnt   = alloc((size_t)(Nn + 1) * 4);
  const size_t o_offs  = alloc((size_t)(Nn + 1) * 4);
  const size_t o_cur   = alloc((size_t)Nn * 4);
  const size_t o_order = alloc((size_t)E * 4);
  const size_t o_flag  = alloc(256);
  const size_t o_log   = alloc((size_t)E * 16);
  const size_t o_attw  = alloc((size_t)E * 16);
  const size_t o_inv   = alloc((size_t)Nn * 16);
  const size_t o_V     = alloc((size_t)E * 256);
  const size_t o_hVb   = alloc((size_t)Nn * 256);
  const size_t o_wbf   = alloc((size_t)115200 * 2);

  if (off > ws_size) {
    fb_kernel<<<(out_size + 255) / 256, 256, 0, stream>>>(hV, (float*)d_out, out_size);
    return;
  }

  int*   idx32  = (int*)(ws + o_idx);
  int*   cnt    = (int*)(ws + o_cnt);
  int*   offsP  = (int*)(ws + o_offs);
  int*   cur    = (int*)(ws + o_cur);
  int*   order  = (int*)(ws + o_order);
  int*   flag   = (int*)(ws + o_flag);
  float* logits = (float*)(ws + o_log);
  float* attw   = (float*)(ws + o_attw);
  float* invd   = (float*)(ws + o_inv);
  u16*   Vb     = (u16*)(ws + o_V);
  u16*   hVb    = (u16*)(ws + o_hVb);
  short* wbf    = (short*)(ws + o_wbf);

  short* W1b = wbf;
  short* W2b = wbf + 49152;
  short* W3b = wbf + 65536;
  short* Wvb = wbf + 66048;
  short* Wob = wbf + 82432;
  short* Wgb = wbf + 98816;

  const int* src = idx32;
  const int* dst = idx32 + E;
  const int nTiles = (E + 63) / 64;

  detect_kernel<<<1, 256, 0, stream>>>((const unsigned*)eidx, flag);
  hipMemsetAsync(cnt, 0, (size_t)(Nn + 1) * 4, stream);
  hipMemsetAsync(cur, 0, (size_t)Nn * 4, stream);
  convert_count_kernel<<<(2 * E + 255) / 256, 256, 0, stream>>>(eidx, idx32, flag, cnt, E);
  scan_kernel<<<1, 1024, 0, stream>>>(cnt, offsP, Nn);
  scatter_kernel<<<(E + 255) / 256, 256, 0, stream>>>(src, offsP, cur, order, E);
  wcvt_kernel<<<(115200 + 255) / 256, 256, 0, stream>>>(B1w, B2w, B3w, WvW, WoW, GW, wbf);
  cvtbf_kernel<<<512, 256, 0, stream>>>(hV, hVb, (long)Nn * 16);

  logits_kernel<<<256, 512, 0, stream>>>(
      hVb, hE, src, dst, W1b, B1b, W2b, B2b, W3b, B3b, logits, E, nTiles);

  vproj_kernel<<<768, 512, 0, stream>>>(hE, Wvb, WvB, Vb, E, nTiles);

  nm_kernel<<<(Nn + 3) / 4, 256, 0, stream>>>(logits, offsP, order, attw, invd, Nn);

  agg_kernel<<<1024, 256, 0, stream>>>(
      hV, attw, invd, Vb, offsP, order, Wob, Wgb, GB, (float*)d_out, Nn);
}

// Round 14
// 653.099 us; speedup vs baseline: 1.0807x; 1.0807x over previous
//
#include <hip/hip_runtime.h>
#include <math.h>

typedef __attribute__((ext_vector_type(8))) short bf16x8;
typedef __attribute__((ext_vector_type(4))) float f32x4;
typedef unsigned short u16;

__device__ __forceinline__ short f2bf(float x) {
  union { float f; unsigned u; } c; c.f = x;
  unsigned u = c.u;
  u += 0x7fffu + ((u >> 16) & 1u);
  return (short)(u >> 16);
}
__device__ __forceinline__ float bf2f(u16 b) {
  union { unsigned u; float f; } c; c.u = ((unsigned)b) << 16; return c.f;
}
__device__ __forceinline__ unsigned pack2(float a, float b) {
  return ((unsigned)(u16)f2bf(a)) | (((unsigned)(u16)f2bf(b)) << 16);
}
__device__ __forceinline__ unsigned cvtpk(float lo, float hi) {
  unsigned r;
  asm("v_cvt_pk_bf16_f32 %0, %1, %2" : "=v"(r) : "v"(lo), "v"(hi));
  return r;
}
__device__ __forceinline__ bf16x8 packfrag(float4 f0, float4 f1) {
  union { uint4 u; bf16x8 v; } cv;
  cv.u.x = cvtpk(f0.x, f0.y); cv.u.y = cvtpk(f0.z, f0.w);
  cv.u.z = cvtpk(f1.x, f1.y); cv.u.w = cvtpk(f1.z, f1.w);
  return cv.v;
}
__device__ __forceinline__ float fast_erf(float x) {
  float ax = fabsf(x);
  float t = __frcp_rn(1.f + 0.3275911f * ax);
  float p = ((((1.061405429f * t - 1.453152027f) * t) + 1.421413741f) * t - 0.284496736f) * t + 0.254829592f;
  float y = 1.f - p * t * __expf(-ax * ax);
  return copysignf(y, x);
}
__device__ __forceinline__ void gload16(const void* g, void* l) {
  __builtin_amdgcn_global_load_lds(
      (const __attribute__((address_space(1))) void*)g,
      (__attribute__((address_space(3))) void*)l, 16, 0, 0);
}

// ---------------- index handling ----------------
__global__ void detect_kernel(const unsigned* __restrict__ idx32, int* __restrict__ flag) {
  __shared__ int anyNZ;
  if (threadIdx.x == 0) anyNZ = 0;
  __syncthreads();
  unsigned v = idx32[threadIdx.x * 2 + 1];
  if (v != 0u) atomicOr(&anyNZ, 1);
  __syncthreads();
  if (threadIdx.x == 0) *flag = (anyNZ == 0) ? 1 : 0;  // 1 => int64 input
}

// convert idx to int32 AND count src occurrences (cnt pre-zeroed)
__global__ void convert_count_kernel(const void* __restrict__ in, int* __restrict__ s32,
                                     const int* __restrict__ flag, int* __restrict__ cnt,
                                     int E) {
  int i = blockIdx.x * 256 + threadIdx.x;
  if (i >= 2 * E) return;
  int f = *flag;
  int v = f ? (int)((const long long*)in)[i] : ((const int*)in)[i];
  s32[i] = v;
  if (i < E) atomicAdd(&cnt[v], 1);
}

__global__ void __launch_bounds__(1024)
scan_kernel(const int* __restrict__ cnt, int* __restrict__ offs, int n) {
  __shared__ int sp[1024];
  int t = threadIdx.x;
  int chunk = (n + 1023) / 1024;
  int begin = t * chunk;
  int end = begin + chunk; if (end > n) end = n; if (begin > n) begin = n;
  int s = 0;
  for (int i = begin; i < end; ++i) s += cnt[i];
  sp[t] = s;
  __syncthreads();
  for (int o = 1; o < 1024; o <<= 1) {
    int v = (t >= o) ? sp[t - o] : 0;
    __syncthreads();
    sp[t] += v;
    __syncthreads();
  }
  int run = (t == 0) ? 0 : sp[t - 1];
  for (int i = begin; i < end; ++i) { offs[i] = run; run += cnt[i]; }
  if (t == 0) offs[n] = sp[1023];
}

// order[p] = original edge index at CSR position p
__global__ void scatter_kernel(const int* __restrict__ src, const int* __restrict__ offs,
                               int* __restrict__ cur, int* __restrict__ order, int E) {
  int i = blockIdx.x * 256 + threadIdx.x;
  if (i >= E) return;
  int s = src[i];
  int p = offs[s] + atomicAdd(&cur[s], 1);
  order[p] = i;
}

// ---------------- weight fp32 -> bf16 ----------------
// layout: W1[49152] | W2[16384] | W3[512] | Wv[16384] | Wo[16384] | Wg[16384]
// W1/W2/Wv are CHUNK-SWIZZLED: chunk c (32 K-cols) stored at
//   chunkBase + row*32 + ((s ^ ((row>>1)&3))<<3) + e   (s = (k%32)/8, e = k%8)
__global__ void wcvt_kernel(const float* __restrict__ B1, const float* __restrict__ B2,
                            const float* __restrict__ B3, const float* __restrict__ Wv,
                            const float* __restrict__ Wo, const float* __restrict__ Wg,
                            short* __restrict__ o) {
  int i = blockIdx.x * 256 + threadIdx.x;
  if (i >= 115200) return;
  float val; int dst;
  if (i < 49152) {
    int row = i / 384, k = i % 384;
    val = B1[i];
    int c = k >> 5, s = (k >> 3) & 3, e = k & 7;
    dst = c * 4096 + row * 32 + ((s ^ ((row >> 1) & 3)) << 3) + e;
  } else if (i < 65536) {
    int j = i - 49152; int row = j >> 7, k = j & 127;
    val = B2[j];
    int c = k >> 5, s = (k >> 3) & 3, e = k & 7;
    dst = 49152 + c * 4096 + row * 32 + ((s ^ ((row >> 1) & 3)) << 3) + e;
  } else if (i < 66048) { val = B3[i - 65536]; dst = i; }
  else if (i < 82432) {
    int j = i - 66048; int row = j >> 7, k = j & 127;
    val = Wv[j];
    int c = k >> 5, s = (k >> 3) & 3, e = k & 7;
    dst = 66048 + c * 4096 + row * 32 + ((s ^ ((row >> 1) & 3)) << 3) + e;
  }
  else if (i < 98816)  { val = Wo[i - 82432]; dst = i; }
  else                 { val = Wg[i - 98816]; dst = i; }
  o[dst] = f2bf(val);
}

// ---------------- fp32 -> bf16 bulk convert (hV only, 5 MB) ----------------
__global__ void cvtbf_kernel(const float* __restrict__ in, u16* __restrict__ out, long n8) {
  long i = (long)blockIdx.x * blockDim.x + threadIdx.x;
  long stride = (long)gridDim.x * blockDim.x;
  for (; i < n8; i += stride) {
    long b = i * 8;
    float4 a = *(const float4*)(in + b);
    float4 c = *(const float4*)(in + b + 4);
    uint4 u;
    u.x = pack2(a.x, a.y); u.y = pack2(a.z, a.w);
    u.z = pack2(c.x, c.y); u.w = pack2(c.z, c.w);
    *(uint4*)(out + b) = u;
  }
}

// ---------------- edge kernel: reg-A + 3-buf 2-ahead counted pipeline ------
// 64 edges/block, 4 waves (2x2 of 32x64). All A-operands in registers
// (aE from hE fp32 pack, aS/aD from hVb) except L2 (sH ds_read). Weight
// chunks flow through sW[3] with vmcnt(2) steady state. Biases in LDS
// (lgkm reads -> vm FIFO stays pure). No vmcnt(0) drain mid-kernel.
#define PSTEP(N, BUF, NEXTP, NBUF, APTR)                                       \
  do {                                                                         \
    asm volatile("s_waitcnt vmcnt(" #N ")" ::: "memory");                      \
    __builtin_amdgcn_sched_barrier(0);                                         \
    __builtin_amdgcn_s_barrier();                                              \
    __builtin_amdgcn_sched_barrier(0);                                         \
    if (NEXTP) STAGE((const short*)(NEXTP), NBUF);                             \
    bf16x8 b_[4];                                                              \
    _Pragma("unroll") for (int nf_ = 0; nf_ < 4; ++nf_) {                      \
      int row_ = wcol + nf_ * 16 + lrow;                                       \
      int seg_ = kgrp ^ ((row_ >> 1) & 3);                                     \
      b_[nf_] = *(const bf16x8*)&sW[BUF][row_ * 32 + seg_ * 8];                \
    }                                                                          \
    _Pragma("unroll") for (int nf_ = 0; nf_ < 4; ++nf_)                        \
      _Pragma("unroll") for (int mi_ = 0; mi_ < 2; ++mi_)                      \
        acc[mi_][nf_] = __builtin_amdgcn_mfma_f32_16x16x32_bf16(               \
            (APTR)[mi_], b_[nf_], acc[mi_][nf_], 0, 0, 0);                     \
  } while (0)

__global__ void __launch_bounds__(256, 3)
edge_kernel(const u16* __restrict__ hVb, const float* __restrict__ hE,
            const int* __restrict__ src, const int* __restrict__ dst,
            u16* __restrict__ Vout,
            const short* __restrict__ W1, const float* __restrict__ b1,
            const short* __restrict__ W2, const float* __restrict__ b2,
            const short* __restrict__ W3b, const float* __restrict__ b3,
            const short* __restrict__ Wv, const float* __restrict__ bv,
            float* __restrict__ logits, int E) {
  __shared__ u16 sH[8192];            // 16KB: V-bounce, then H
  __shared__ u16 sW[3][4096];         // 24KB: 3-deep chunk pipeline
  __shared__ float sBias[896];        // 3.5KB: b1|bv|b2|W3(f32)

  const int t = threadIdx.x;
  const int eBase = blockIdx.x * 64;
  const int lane = t & 63;
  const int wid = t >> 6;
  const int wrow = (wid >> 1) * 32;
  const int wcol = (wid & 1) * 64;
  const int lrow = lane & 15;
  const int kgrp = lane >> 4;

  auto STAGE = [&](const short* cp, int buf) {
#pragma unroll
    for (int i = 0; i < 2; ++i) {
      int L = t + i * 256;
      gload16(cp + L * 8, &sW[buf][L * 8]);
    }
  };

  // ---- prologue: biases -> LDS; A-operands -> regs; then stage c0,c1 ----
  if (t < 128) {
    sBias[t] = b1[t];
    sBias[128 + t] = bv[t];
    sBias[256 + t] = b2[t];
  }
  {
    int i0 = t * 2;
    sBias[384 + i0] = bf2f((u16)W3b[i0]);
    sBias[384 + i0 + 1] = bf2f((u16)W3b[i0 + 1]);
  }

  bf16x8 aE[4][2], aS[4][2], aD[4][2];
  {
    int rS[2], rD[2], rE[2];
#pragma unroll
    for (int mi = 0; mi < 2; ++mi) {
      int e = min(eBase + wrow + mi * 16 + lrow, E - 1);
      rS[mi] = src[e]; rD[mi] = dst[e]; rE[mi] = e;
    }
#pragma unroll
    for (int c4 = 0; c4 < 4; ++c4) {
      const int kk = c4 * 32 + kgrp * 8;
#pragma unroll
      for (int mi = 0; mi < 2; ++mi) {
        const float* p = hE + (size_t)rE[mi] * 128 + kk;
        aE[c4][mi] = packfrag(*(const float4*)p, *(const float4*)(p + 4));
        aS[c4][mi] = *(const bf16x8*)(hVb + (size_t)rS[mi] * 128 + kk);
        aD[c4][mi] = *(const bf16x8*)(hVb + (size_t)rD[mi] * 128 + kk);
      }
    }
  }
#pragma unroll
  for (int c4 = 0; c4 < 4; ++c4)
#pragma unroll
    for (int mi = 0; mi < 2; ++mi)
      asm volatile("" :: "v"(aE[c4][mi]), "v"(aS[c4][mi]), "v"(aD[c4][mi]));

  STAGE(Wv, 0);                 // c0
  STAGE(Wv + 4096, 1);          // c1
  asm volatile("s_waitcnt vmcnt(4) lgkmcnt(0)" ::: "memory");
  __builtin_amdgcn_sched_barrier(0);
  __builtin_amdgcn_s_barrier();

  f32x4 acc[2][4];
  auto ZACC = [&]() {
#pragma unroll
    for (int mi = 0; mi < 2; ++mi)
#pragma unroll
      for (int nf = 0; nf < 4; ++nf)
#pragma unroll
        for (int q = 0; q < 4; ++q) acc[mi][nf][q] = 0.f;
  };
  auto LDSA = [&](int kk, bf16x8* a) {
#pragma unroll
    for (int mi = 0; mi < 2; ++mi) {
      int row = wrow + mi * 16 + lrow;
      int seg = (kk >> 3) ^ (row & 15);
      a[mi] = *(const bf16x8*)&sH[row * 128 + seg * 8];
    }
  };

  // ---------------- V phase: chunks 0..3 (Wv x aE) ----------------
  ZACC();
  PSTEP(2, 0, Wv + 2 * 4096, 2, aE[0]);   // c0, stage c2
  PSTEP(2, 1, Wv + 3 * 4096, 0, aE[1]);   // c1, stage c3
  PSTEP(2, 2, W1,            1, aE[2]);   // c2, stage c4
  PSTEP(2, 0, W1 + 4096,     2, aE[3]);   // c3, stage c5

  // ---- V epilogue: gelu -> sH bounce -> coalesced store ----
#pragma unroll
  for (int mi = 0; mi < 2; ++mi)
#pragma unroll
    for (int nf = 0; nf < 4; ++nf)
#pragma unroll
      for (int q = 0; q < 4; ++q) {
        int row = wrow + mi * 16 + kgrp * 4 + q;
        int col = wcol + nf * 16 + lrow;
        float x = acc[mi][nf][q] + sBias[128 + col];
        float g = 0.5f * x * (1.0f + fast_erf(x * 0.70710678118654752f));
        int seg = (col >> 3) ^ (row & 15);
        sH[row * 128 + seg * 8 + (col & 7)] = (u16)f2bf(g);
      }
  asm volatile("s_waitcnt lgkmcnt(0)" ::: "memory");
  __builtin_amdgcn_sched_barrier(0);
  __builtin_amdgcn_s_barrier();
#pragma unroll
  for (int i = 0; i < 4; ++i) {
    int u = t + i * 256;
    int row = u >> 4, g16 = u & 15;
    int seg = g16 ^ (row & 15);
    uint4 v = *(const uint4*)&sH[row * 128 + seg * 8];
    int e = eBase + row;
    if (e < E) *(uint4*)(Vout + (size_t)e * 128 + g16 * 8) = v;   // 4 stores -> FIFO
  }
  __builtin_amdgcn_sched_barrier(0);

  // ---------------- layer 1: chunks 4..15 (W1) ----------------
  ZACC();
  PSTEP(6, 1, W1 + 2 * 4096, 0, aS[0]);   // c4  (stores ahead in FIFO)
  PSTEP(6, 2, W1 + 3 * 4096, 1, aS[1]);   // c5
  PSTEP(2, 0, W1 + 4 * 4096, 2, aS[2]);   // c6  (drains stores + c6)
  PSTEP(2, 1, W1 + 5 * 4096, 0, aS[3]);   // c7
  PSTEP(2, 2, W1 + 6 * 4096, 1, aE[0]);   // c8
  PSTEP(2, 0, W1 + 7 * 4096, 2, aE[1]);   // c9
  PSTEP(2, 1, W1 + 8 * 4096, 0, aE[2]);   // c10
  PSTEP(2, 2, W1 + 9 * 4096, 1, aE[3]);   // c11
  PSTEP(2, 0, W1 + 10 * 4096, 2, aD[0]);  // c12
  PSTEP(2, 1, W1 + 11 * 4096, 0, aD[1]);  // c13
  PSTEP(2, 2, W2,             1, aD[2]);  // c14, stage c16
  PSTEP(2, 0, W2 + 4096,      2, aD[3]);  // c15, stage c17

  // ---- L1 epilogue: relu(acc+b1) -> sH ----
#pragma unroll
  for (int mi = 0; mi < 2; ++mi)
#pragma unroll
    for (int nf = 0; nf < 4; ++nf)
#pragma unroll
      for (int q = 0; q < 4; ++q) {
        int row = wrow + mi * 16 + kgrp * 4 + q;
        int col = wcol + nf * 16 + lrow;
        int seg = (col >> 3) ^ (row & 15);
        sH[row * 128 + seg * 8 + (col & 7)] =
            (u16)f2bf(fmaxf(acc[mi][nf][q] + sBias[col], 0.f));
      }
  asm volatile("s_waitcnt lgkmcnt(0)" ::: "memory");
  __builtin_amdgcn_sched_barrier(0);
  __builtin_amdgcn_s_barrier();   // raw: no vmcnt drain; c16/c17 stay in flight

  // ---------------- layer 2: chunks 16..19 (W2 x sH) ----------------
  ZACC();
  { bf16x8 a_[2]; LDSA(0 * 32 + kgrp * 8, a_); PSTEP(2, 1, W2 + 2 * 4096, 0, a_); }  // c16
  { bf16x8 a_[2]; LDSA(1 * 32 + kgrp * 8, a_); PSTEP(2, 2, W2 + 3 * 4096, 1, a_); }  // c17
  { bf16x8 a_[2]; LDSA(2 * 32 + kgrp * 8, a_); PSTEP(2, 0, (const short*)0, 0, a_); } // c18
  { bf16x8 a_[2]; LDSA(3 * 32 + kgrp * 8, a_); PSTEP(0, 1, (const short*)0, 0, a_); } // c19

  // ---- L2 epilogue (+ folded layer 3); sPart aliases sW[2] (dead) ----
  {
    float* sPart = (float*)&sW[2][0];   // [64][4][2] floats = 2KB
    float b2c[4], w3v[4][4];
#pragma unroll
    for (int nf = 0; nf < 4; ++nf) {
      int col = wcol + nf * 16 + lrow;
      b2c[nf] = sBias[256 + col];
#pragma unroll
      for (int h = 0; h < 4; ++h) w3v[h][nf] = sBias[384 + h * 128 + col];
    }
#pragma unroll
    for (int mi = 0; mi < 2; ++mi)
#pragma unroll
      for (int q = 0; q < 4; ++q) {
        float p0 = 0.f, p1 = 0.f, p2 = 0.f, p3 = 0.f;
#pragma unroll
        for (int nf = 0; nf < 4; ++nf) {
          float x = fmaxf(acc[mi][nf][q] + b2c[nf], 0.f);
          p0 += x * w3v[0][nf]; p1 += x * w3v[1][nf];
          p2 += x * w3v[2][nf]; p3 += x * w3v[3][nf];
        }
#pragma unroll
        for (int o = 1; o < 16; o <<= 1) {
          p0 += __shfl_xor(p0, o); p1 += __shfl_xor(p1, o);
          p2 += __shfl_xor(p2, o); p3 += __shfl_xor(p3, o);
        }
        if (lrow < 4) {
          float pw = (lrow == 0) ? p0 : (lrow == 1) ? p1 : (lrow == 2) ? p2 : p3;
          sPart[(wrow + mi * 16 + kgrp * 4 + q) * 8 + lrow * 2 + (wid & 1)] = pw;
        }
      }
    asm volatile("s_waitcnt lgkmcnt(0)" ::: "memory");
    __builtin_amdgcn_sched_barrier(0);
    __builtin_amdgcn_s_barrier();
    if (t < 256) {
      int r = t >> 2, h = t & 3;
      float lg = (sPart[r * 8 + h * 2] + sPart[r * 8 + h * 2 + 1] + b3[h])
                 * 0.17677669529663687f;
      int e = eBase + r;
      if (e < E) logits[(size_t)e * 4 + h] = lg;
    }
  }
}

// ---------------- node kernels (order-indirected) ----------------
__global__ void __launch_bounds__(256)
nm_kernel(const float* __restrict__ logits, const int* __restrict__ offs,
          const int* __restrict__ order, float* __restrict__ attw,
          float* __restrict__ inv, int nN) {
  const int wid = threadIdx.x >> 6, lane = threadIdx.x & 63;
  const int nW = gridDim.x * 4;
  for (int v = blockIdx.x * 4 + wid; v < nN; v += nW) {
    const int base = offs[v];
    const int deg = offs[v + 1] - base;
    float m0 = -3e38f, m1 = -3e38f, m2 = -3e38f, m3 = -3e38f;
    for (int i = lane; i < deg; i += 64) {
      int e = order[base + i];
      float4 l = *(const float4*)(logits + (size_t)e * 4);
      m0 = fmaxf(m0, l.x); m1 = fmaxf(m1, l.y);
      m2 = fmaxf(m2, l.z); m3 = fmaxf(m3, l.w);
    }
#pragma unroll
    for (int o = 32; o > 0; o >>= 1) {
      m0 = fmaxf(m0, __shfl_xor(m0, o)); m1 = fmaxf(m1, __shfl_xor(m1, o));
      m2 = fmaxf(m2, __shfl_xor(m2, o)); m3 = fmaxf(m3, __shfl_xor(m3, o));
    }
    float d0 = 0.f, d1 = 0.f, d2 = 0.f, d3 = 0.f;
    for (int i = lane; i < deg; i += 64) {
      int e = order[base + i];
      float4 l = *(const float4*)(logits + (size_t)e * 4);
      float4 ex;
      ex.x = __expf(l.x - m0); ex.y = __expf(l.y - m1);
      ex.z = __expf(l.z - m2); ex.w = __expf(l.w - m3);
      *(float4*)(attw + (size_t)e * 4) = ex;
      d0 += ex.x; d1 += ex.y; d2 += ex.z; d3 += ex.w;
    }
#pragma unroll
    for (int o = 32; o > 0; o >>= 1) {
      d0 += __shfl_xor(d0, o); d1 += __shfl_xor(d1, o);
      d2 += __shfl_xor(d2, o); d3 += __shfl_xor(d3, o);
    }
    if (lane < 4) {
      float dv = (lane == 0) ? d0 : (lane == 1) ? d1 : (lane == 2) ? d2 : d3;
      inv[(size_t)v * 4 + lane] = (dv > 0.f) ? 1.f / dv : 0.f;
    }
  }
}

__device__ __forceinline__ float dot8(const float* ag, uint4 w) {
  unsigned wr[4] = {w.x, w.y, w.z, w.w};
  float s = 0.f;
#pragma unroll
  for (int q = 0; q < 4; ++q) {
    s += ag[2 * q]     * bf2f((u16)(wr[q] & 0xffffu));
    s += ag[2 * q + 1] * bf2f((u16)(wr[q] >> 16));
  }
  return s;
}

// one node per WAVE; lane = 16 dim-groups x 4 edge-slots (16B V loads);
// Wo/Wg cached in LDS (XOR-swizzled); grid-stride over nodes.
__global__ void __launch_bounds__(256, 2)
agg_kernel(const float* __restrict__ hV, const float* __restrict__ attw,
           const float* __restrict__ inv, const u16* __restrict__ V,
           const int* __restrict__ offs, const int* __restrict__ order,
           const short* __restrict__ Wob, const short* __restrict__ Wgb,
           const float* __restrict__ gb, float* __restrict__ out, int nN) {
  __shared__ u16 sW[2][16384];      // 64KB
  __shared__ float sAgg[4][132];
  const int t = threadIdx.x;
#pragma unroll
  for (int i = 0; i < 8; ++i) {
    int idx = t + i * 256;          // 0..2047 uint4 per matrix
    int row = idx >> 4, k16 = idx & 15;
    int di = row * 128 + ((k16 ^ (row & 15)) * 8);
    *(uint4*)&sW[0][di] = ((const uint4*)Wob)[idx];
    *(uint4*)&sW[1][di] = ((const uint4*)Wgb)[idx];
  }
  __syncthreads();
  const int wid = t >> 6, lane = t & 63;
  const int dgrp = lane & 15, egrp = lane >> 4, h = dgrp >> 2;
  const int j0 = lane, j1 = lane + 64;
  const int s0 = (j0 & 15), s1 = (j1 & 15);
  for (int v = blockIdx.x * 4 + wid; v < nN; v += gridDim.x * 4) {
    const int base = offs[v], deg = offs[v + 1] - base;
    float a[8];
#pragma unroll
    for (int q = 0; q < 8; ++q) a[q] = 0.f;
    for (int i = egrp; i < deg; i += 4) {
      int e = order[base + i];
      float w = attw[(size_t)e * 4 + h];
      bf16x8 vv = *(const bf16x8*)(V + (size_t)e * 128 + dgrp * 8);
#pragma unroll
      for (int q = 0; q < 8; ++q) a[q] += w * bf2f((u16)vv[q]);
    }
#pragma unroll
    for (int q = 0; q < 8; ++q) {
      a[q] += __shfl_xor(a[q], 16);
      a[q] += __shfl_xor(a[q], 32);
    }
    if (egrp == 0) {
      float innv = inv[(size_t)v * 4 + h];
#pragma unroll
      for (int q = 0; q < 8; ++q) sAgg[wid][dgrp * 8 + q] = a[q] * innv;
    }
    asm volatile("s_waitcnt lgkmcnt(0)" ::: "memory");
    __builtin_amdgcn_wave_barrier();
    float o0 = 0.f, o1 = 0.f, g0 = 0.f, g1 = 0.f;
#pragma unroll 4
    for (int k = 0; k < 128; k += 8) {
      float a8[8];
#pragma unroll
      for (int q = 0; q < 8; ++q) a8[q] = sAgg[wid][k + q];
      int k16 = k >> 3;
      uint4 wo0 = *(const uint4*)&sW[0][j0 * 128 + ((k16 ^ s0) * 8)];
      uint4 wo1 = *(const uint4*)&sW[0][j1 * 128 + ((k16 ^ s1) * 8)];
      uint4 wg0 = *(const uint4*)&sW[1][j0 * 128 + ((k16 ^ s0) * 8)];
      uint4 wg1 = *(const uint4*)&sW[1][j1 * 128 + ((k16 ^ s1) * 8)];
      o0 += dot8(a8, wo0); o1 += dot8(a8, wo1);
      g0 += dot8(a8, wg0); g1 += dot8(a8, wg1);
    }
    float gg0 = 1.f / (1.f + __expf(-(g0 + gb[j0])));
    float gg1 = 1.f / (1.f + __expf(-(g1 + gb[j1])));
    out[(size_t)v * 128 + j0] = hV[(size_t)v * 128 + j0] + o0 * gg0;
    out[(size_t)v * 128 + j1] = hV[(size_t)v * 128 + j1] + o1 * gg1;
    asm volatile("s_waitcnt lgkmcnt(0)" ::: "memory");
    __builtin_amdgcn_wave_barrier();
  }
}

// ---------------- fallback (ws too small marker) ----------------
__global__ void fb_kernel(const float* __restrict__ hV, float* __restrict__ out, int n) {
  int i = blockIdx.x * 256 + threadIdx.x;
  if (i < n) out[i] = hV[i] + 0.5f;
}

extern "C" void kernel_launch(void* const* d_in, const int* in_sizes, int n_in,
                              void* d_out, int out_size, void* d_ws, size_t ws_size,
                              hipStream_t stream) {
  const float* hV   = (const float*)d_in[0];
  const float* hE   = (const float*)d_in[1];
  const void*  eidx = d_in[2];
  const float* WvW  = (const float*)d_in[3];
  const float* WvB  = (const float*)d_in[4];
  const float* B1w  = (const float*)d_in[5];
  const float* B1b  = (const float*)d_in[6];
  const float* B2w  = (const float*)d_in[7];
  const float* B2b  = (const float*)d_in[8];
  const float* B3w  = (const float*)d_in[9];
  const float* B3b  = (const float*)d_in[10];
  const float* WoW  = (const float*)d_in[11];
  const float* GW   = (const float*)d_in[12];
  const float* GB   = (const float*)d_in[13];

  const int Nn = in_sizes[0] / 128;
  const int E  = in_sizes[1] / 128;
  if (Nn <= 0 || E <= 0) return;

  char* ws = (char*)d_ws;
  size_t off = 0;
  auto alloc = [&](size_t b) { size_t o = off; off += (b + 255) & ~(size_t)255; return o; };
  const size_t o_idx   = alloc((size_t)2 * E * 4);
  const size_t o_cnt   = alloc((size_t)(Nn + 1) * 4);
  const size_t o_offs  = alloc((size_t)(Nn + 1) * 4);
  const size_t o_cur   = alloc((size_t)Nn * 4);
  const size_t o_order = alloc((size_t)E * 4);
  const size_t o_flag  = alloc(256);
  const size_t o_log   = alloc((size_t)E * 16);
  const size_t o_attw  = alloc((size_t)E * 16);
  const size_t o_inv   = alloc((size_t)Nn * 16);
  const size_t o_V     = alloc((size_t)E * 256);
  const size_t o_hVb   = alloc((size_t)Nn * 256);
  const size_t o_wbf   = alloc((size_t)115200 * 2);

  if (off > ws_size) {
    fb_kernel<<<(out_size + 255) / 256, 256, 0, stream>>>(hV, (float*)d_out, out_size);
    return;
  }

  int*   idx32  = (int*)(ws + o_idx);
  int*   cnt    = (int*)(ws + o_cnt);
  int*   offsP  = (int*)(ws + o_offs);
  int*   cur    = (int*)(ws + o_cur);
  int*   order  = (int*)(ws + o_order);
  int*   flag   = (int*)(ws + o_flag);
  float* logits = (float*)(ws + o_log);
  float* attw   = (float*)(ws + o_attw);
  float* invd   = (float*)(ws + o_inv);
  u16*   Vb     = (u16*)(ws + o_V);
  u16*   hVb    = (u16*)(ws + o_hVb);
  short* wbf    = (short*)(ws + o_wbf);

  short* W1b = wbf;
  short* W2b = wbf + 49152;
  short* W3b = wbf + 65536;
  short* Wvb = wbf + 66048;
  short* Wob = wbf + 82432;
  short* Wgb = wbf + 98816;

  const int* src = idx32;
  const int* dst = idx32 + E;

  detect_kernel<<<1, 256, 0, stream>>>((const unsigned*)eidx, flag);
  hipMemsetAsync(cnt, 0, (size_t)(Nn + 1) * 4, stream);
  hipMemsetAsync(cur, 0, (size_t)Nn * 4, stream);
  convert_count_kernel<<<(2 * E + 255) / 256, 256, 0, stream>>>(eidx, idx32, flag, cnt, E);
  scan_kernel<<<1, 1024, 0, stream>>>(cnt, offsP, Nn);
  scatter_kernel<<<(E + 255) / 256, 256, 0, stream>>>(src, offsP, cur, order, E);
  wcvt_kernel<<<(115200 + 255) / 256, 256, 0, stream>>>(B1w, B2w, B3w, WvW, WoW, GW, wbf);
  cvtbf_kernel<<<512, 256, 0, stream>>>(hV, hVb, (long)Nn * 16);

  edge_kernel<<<(E + 63) / 64, 256, 0, stream>>>(
      hVb, hE, src, dst, Vb, W1b, B1b, W2b, B2b, W3b, B3b, Wvb, WvB, logits, E);

  nm_kernel<<<(Nn + 3) / 4, 256, 0, stream>>>(logits, offsP, order, attw, invd, Nn);

  agg_kernel<<<1024, 256, 0, stream>>>(
      hV, attw, invd, Vb, offsP, order, Wob, Wgb, GB, (float*)d_out, Nn);
}

// Round 15
// 557.751 us; speedup vs baseline: 1.2655x; 1.1710x over previous
//
#include <hip/hip_runtime.h>
#include <math.h>

typedef __attribute__((ext_vector_type(8))) short bf16x8;
typedef __attribute__((ext_vector_type(4))) float f32x4;
typedef unsigned short u16;

__device__ __forceinline__ short f2bf(float x) {
  union { float f; unsigned u; } c; c.f = x;
  unsigned u = c.u;
  u += 0x7fffu + ((u >> 16) & 1u);
  return (short)(u >> 16);
}
__device__ __forceinline__ float bf2f(u16 b) {
  union { unsigned u; float f; } c; c.u = ((unsigned)b) << 16; return c.f;
}
__device__ __forceinline__ unsigned pack2(float a, float b) {
  return ((unsigned)(u16)f2bf(a)) | (((unsigned)(u16)f2bf(b)) << 16);
}
__device__ __forceinline__ unsigned cvtpk(float lo, float hi) {
  unsigned r;
  asm("v_cvt_pk_bf16_f32 %0, %1, %2" : "=v"(r) : "v"(lo), "v"(hi));
  return r;
}
__device__ __forceinline__ float fast_erf(float x) {
  float ax = fabsf(x);
  float t = __frcp_rn(1.f + 0.3275911f * ax);
  float p = ((((1.061405429f * t - 1.453152027f) * t) + 1.421413741f) * t - 0.284496736f) * t + 0.254829592f;
  float y = 1.f - p * t * __expf(-ax * ax);
  return copysignf(y, x);
}
__device__ __forceinline__ void gload16(const void* g, void* l) {
  __builtin_amdgcn_global_load_lds(
      (const __attribute__((address_space(1))) void*)g,
      (__attribute__((address_space(3))) void*)l, 16, 0, 0);
}

// ---------------- index handling ----------------
__global__ void detect_kernel(const unsigned* __restrict__ idx32, int* __restrict__ flag) {
  __shared__ int anyNZ;
  if (threadIdx.x == 0) anyNZ = 0;
  __syncthreads();
  unsigned v = idx32[threadIdx.x * 2 + 1];
  if (v != 0u) atomicOr(&anyNZ, 1);
  __syncthreads();
  if (threadIdx.x == 0) *flag = (anyNZ == 0) ? 1 : 0;  // 1 => int64 input
}

// convert idx to int32 AND count src occurrences (cnt pre-zeroed)
__global__ void convert_count_kernel(const void* __restrict__ in, int* __restrict__ s32,
                                     const int* __restrict__ flag, int* __restrict__ cnt,
                                     int E) {
  int i = blockIdx.x * 256 + threadIdx.x;
  if (i >= 2 * E) return;
  int f = *flag;
  int v = f ? (int)((const long long*)in)[i] : ((const int*)in)[i];
  s32[i] = v;
  if (i < E) atomicAdd(&cnt[v], 1);
}

__global__ void __launch_bounds__(1024)
scan_kernel(const int* __restrict__ cnt, int* __restrict__ offs, int n) {
  __shared__ int sp[1024];
  int t = threadIdx.x;
  int chunk = (n + 1023) / 1024;
  int begin = t * chunk;
  int end = begin + chunk; if (end > n) end = n; if (begin > n) begin = n;
  int s = 0;
  for (int i = begin; i < end; ++i) s += cnt[i];
  sp[t] = s;
  __syncthreads();
  for (int o = 1; o < 1024; o <<= 1) {
    int v = (t >= o) ? sp[t - o] : 0;
    __syncthreads();
    sp[t] += v;
    __syncthreads();
  }
  int run = (t == 0) ? 0 : sp[t - 1];
  for (int i = begin; i < end; ++i) { offs[i] = run; run += cnt[i]; }
  if (t == 0) offs[n] = sp[1023];
}

// order[p] = original edge index at CSR position p
__global__ void scatter_kernel(const int* __restrict__ src, const int* __restrict__ offs,
                               int* __restrict__ cur, int* __restrict__ order, int E) {
  int i = blockIdx.x * 256 + threadIdx.x;
  if (i >= E) return;
  int s = src[i];
  int p = offs[s] + atomicAdd(&cur[s], 1);
  order[p] = i;
}

// ---------------- weight fp32 -> bf16 ----------------
// layout: W1[49152] | W2[16384] | W3[512] | Wv[16384] | Wo[16384] | Wg[16384]
// W1/W2/Wv are CHUNK-SWIZZLED for LDS staging: chunk c (32 K-cols) stored as
//   chunkBase + row*32 + ((s ^ ((row>>1)&3))<<3) + e   (s = (k%32)/8, e = k%8)
// so global_load_lds (linear dest) + swizzled ds_read_b128 is bank-uniform.
__global__ void wcvt_kernel(const float* __restrict__ B1, const float* __restrict__ B2,
                            const float* __restrict__ B3, const float* __restrict__ Wv,
                            const float* __restrict__ Wo, const float* __restrict__ Wg,
                            short* __restrict__ o) {
  int i = blockIdx.x * 256 + threadIdx.x;
  if (i >= 115200) return;
  float val; int dst;
  if (i < 49152) {
    int row = i / 384, k = i % 384;
    val = B1[i];
    int c = k >> 5, s = (k >> 3) & 3, e = k & 7;
    dst = c * 4096 + row * 32 + ((s ^ ((row >> 1) & 3)) << 3) + e;
  } else if (i < 65536) {
    int j = i - 49152; int row = j >> 7, k = j & 127;
    val = B2[j];
    int c = k >> 5, s = (k >> 3) & 3, e = k & 7;
    dst = 49152 + c * 4096 + row * 32 + ((s ^ ((row >> 1) & 3)) << 3) + e;
  } else if (i < 66048) { val = B3[i - 65536]; dst = i; }
  else if (i < 82432) {
    int j = i - 66048; int row = j >> 7, k = j & 127;
    val = Wv[j];
    int c = k >> 5, s = (k >> 3) & 3, e = k & 7;
    dst = 66048 + c * 4096 + row * 32 + ((s ^ ((row >> 1) & 3)) << 3) + e;
  }
  else if (i < 98816)  { val = Wo[i - 82432]; dst = i; }
  else                 { val = Wg[i - 98816]; dst = i; }
  o[dst] = f2bf(val);
}

// ---------------- fp32 -> bf16 bulk convert (hV only, 5 MB) ----------------
__global__ void cvtbf_kernel(const float* __restrict__ in, u16* __restrict__ out, long n8) {
  long i = (long)blockIdx.x * blockDim.x + threadIdx.x;
  long stride = (long)gridDim.x * blockDim.x;
  for (; i < n8; i += stride) {
    long b = i * 8;
    float4 a = *(const float4*)(in + b);
    float4 c = *(const float4*)(in + b + 4);
    uint4 u;
    u.x = pack2(a.x, a.y); u.y = pack2(a.z, a.w);
    u.z = pack2(c.x, c.y); u.w = pack2(c.z, c.w);
    *(uint4*)(out + b) = u;
  }
}

// ---------------- edge kernel: LDS-staged double-buffered weights ----------
// 64 edges/block, 256 threads = 4 waves (2x2 of 32x64 tiles). 20 chunk-steps:
//   STAGE(next chunk via global_load_lds) -> ds_read B (swizzled, uniform)
//   -> 8 MFMA -> vmcnt(0) -> barrier.
// A: hVb src/dst hoisted to regs; hE staged once to sE (bf16, swizzled).
__global__ void __launch_bounds__(256, 3)
edge_kernel(const u16* __restrict__ hVb, const float* __restrict__ hE,
            const int* __restrict__ src, const int* __restrict__ dst,
            u16* __restrict__ Vout,
            const short* __restrict__ W1, const float* __restrict__ b1,
            const short* __restrict__ W2, const float* __restrict__ b2,
            const short* __restrict__ W3b, const float* __restrict__ b3,
            const short* __restrict__ Wv, const float* __restrict__ bv,
            float* __restrict__ logits, int E) {
  __shared__ u16 sE[64 * 128];        // 16KB, seg ^= row&15
  __shared__ u16 sH[64 * 128];        // 16KB
  __shared__ u16 sW[2][4096];         // 2 x 8KB weight chunk double-buffer
  __shared__ float sPart[64][4][2];   // 2KB

  const int t = threadIdx.x;
  const int eBase = blockIdx.x * 64;
  const int lane = t & 63;
  const int wid = t >> 6;
  const int wrow = (wid >> 1) * 32;
  const int wcol = (wid & 1) * 64;
  const int lrow = lane & 15;
  const int kgrp = lane >> 4;

  auto STAGE = [&](const short* cp, int buf) {
#pragma unroll
    for (int i = 0; i < 2; ++i) {
      int L = t + i * 256;
      gload16(cp + L * 8, &sW[buf][L * 8]);
    }
  };

  // ---- prologue: stage chunk 0 (async), then hE + hoisting work ----
  STAGE(W1, 0);

  // stage hE (fp32 contiguous) -> sE bf16, swizzled
#pragma unroll
  for (int i = 0; i < 4; ++i) {
    int u = t + i * 256;             // 0..1023 8-float units
    int row = u >> 4, sg = u & 15;
    const float* p = hE + (size_t)min(eBase + row, E - 1) * 128 + sg * 8;
    float4 f0 = *(const float4*)p;
    float4 f1 = *(const float4*)(p + 4);
    uint4 cv;
    cv.x = cvtpk(f0.x, f0.y); cv.y = cvtpk(f0.z, f0.w);
    cv.z = cvtpk(f1.x, f1.y); cv.w = cvtpk(f1.z, f1.w);
    *(uint4*)&sE[row * 128 + ((sg ^ (row & 15)) * 8)] = cv;
  }

  // hoist ALL hVb gathers (src & dst) into registers
  bf16x8 aS[4][2], aD[4][2];
  {
    int rS[2], rD[2];
#pragma unroll
    for (int mi = 0; mi < 2; ++mi) {
      int e = min(eBase + wrow + mi * 16 + lrow, E - 1);
      rS[mi] = src[e];
      rD[mi] = dst[e];
    }
#pragma unroll
    for (int c4 = 0; c4 < 4; ++c4) {
      const int kk = c4 * 32 + kgrp * 8;
#pragma unroll
      for (int mi = 0; mi < 2; ++mi) {
        aS[c4][mi] = *(const bf16x8*)(hVb + (size_t)rS[mi] * 128 + kk);
        aD[c4][mi] = *(const bf16x8*)(hVb + (size_t)rD[mi] * 128 + kk);
      }
    }
  }
  asm volatile("s_waitcnt vmcnt(0)" ::: "memory");
  __syncthreads();

  f32x4 acc[2][4];
  auto ZACC = [&]() {
#pragma unroll
    for (int mi = 0; mi < 2; ++mi)
#pragma unroll
      for (int nf = 0; nf < 4; ++nf)
#pragma unroll
        for (int q = 0; q < 4; ++q) acc[mi][nf][q] = 0.f;
  };
  auto LDSA = [&](const u16* s, int kk, bf16x8* a) {
#pragma unroll
    for (int mi = 0; mi < 2; ++mi) {
      int row = wrow + mi * 16 + lrow;
      int seg = (kk >> 3) ^ (row & 15);
      a[mi] = *(const bf16x8*)&s[row * 128 + seg * 8];
    }
  };
  // one pipelined chunk-step
  auto STEP = [&](int buf, const short* nextCp, const bf16x8* a) {
    if (nextCp) STAGE(nextCp, buf ^ 1);
    bf16x8 b[4];
#pragma unroll
    for (int nf = 0; nf < 4; ++nf) {
      int row = wcol + nf * 16 + lrow;
      int seg = kgrp ^ ((row >> 1) & 3);
      b[nf] = *(const bf16x8*)&sW[buf][row * 32 + seg * 8];
    }
#pragma unroll
    for (int nf = 0; nf < 4; ++nf)
#pragma unroll
      for (int mi = 0; mi < 2; ++mi)
        acc[mi][nf] = __builtin_amdgcn_mfma_f32_16x16x32_bf16(a[mi], b[nf], acc[mi][nf], 0, 0, 0);
    if (nextCp) asm volatile("s_waitcnt vmcnt(0)" ::: "memory");
    __syncthreads();
  };

  // ---------------- layer 1: chunks 0..11 ----------------
  ZACC();
  STEP(0, W1 + 1 * 4096, aS[0]);
  STEP(1, W1 + 2 * 4096, aS[1]);
  STEP(0, W1 + 3 * 4096, aS[2]);
  STEP(1, W1 + 4 * 4096, aS[3]);
#pragma unroll
  for (int c4 = 0; c4 < 4; ++c4) {
    bf16x8 a[2];
    LDSA(sE, c4 * 32 + kgrp * 8, a);
    STEP((4 + c4) & 1, W1 + (5 + c4) * 4096, a);
  }
  STEP(0, W1 + 9 * 4096, aD[0]);
  STEP(1, W1 + 10 * 4096, aD[1]);
  STEP(0, W1 + 11 * 4096, aD[2]);
  STEP(1, Wv, aD[3]);
  // epilogue 1: sH = relu(acc + b1), swizzled
  {
    float b1c[4];
#pragma unroll
    for (int nf = 0; nf < 4; ++nf) b1c[nf] = b1[wcol + nf * 16 + lrow];
#pragma unroll
    for (int mi = 0; mi < 2; ++mi)
#pragma unroll
      for (int nf = 0; nf < 4; ++nf)
#pragma unroll
        for (int q = 0; q < 4; ++q) {
          int row = wrow + mi * 16 + kgrp * 4 + q;
          int col = wcol + nf * 16 + lrow;
          int seg = (col >> 3) ^ (row & 15);
          sH[row * 128 + seg * 8 + (col & 7)] =
              (u16)f2bf(fmaxf(acc[mi][nf][q] + b1c[nf], 0.f));
        }
  }

  // ---------------- V = gelu(sE @ Wv^T + bv): chunks 12..15 ----------------
  ZACC();
#pragma unroll
  for (int v = 0; v < 4; ++v) {
    bf16x8 a[2];
    LDSA(sE, v * 32 + kgrp * 8, a);
    const short* nxt = (v < 3) ? (Wv + (v + 1) * 4096) : W2;
    STEP(v & 1, nxt, a);
  }
  // V epilogue: gelu -> sE (dead after step 15), swizzled
  {
    float bvc[4];
#pragma unroll
    for (int nf = 0; nf < 4; ++nf) bvc[nf] = bv[wcol + nf * 16 + lrow];
#pragma unroll
    for (int mi = 0; mi < 2; ++mi)
#pragma unroll
      for (int nf = 0; nf < 4; ++nf)
#pragma unroll
        for (int q = 0; q < 4; ++q) {
          int row = wrow + mi * 16 + kgrp * 4 + q;
          int col = wcol + nf * 16 + lrow;
          float x = acc[mi][nf][q] + bvc[nf];
          float g = 0.5f * x * (1.0f + fast_erf(x * 0.70710678118654752f));
          int seg = (col >> 3) ^ (row & 15);
          sE[row * 128 + seg * 8 + (col & 7)] = (u16)f2bf(g);
        }
  }
  __syncthreads();
  // coalesced V store (original order)
#pragma unroll
  for (int i = 0; i < 4; ++i) {
    int u = t + i * 256;             // 0..1023 16B-lines
    int row = u >> 4, g16 = u & 15;
    int seg = g16 ^ (row & 15);
    uint4 v = *(const uint4*)&sE[row * 128 + seg * 8];
    int e = eBase + row;
    if (e < E) *(uint4*)(Vout + (size_t)e * 128 + g16 * 8) = v;
  }

  // ---------------- layer 2 (+ folded layer 3): chunks 16..19 --------------
  ZACC();
#pragma unroll
  for (int u = 0; u < 4; ++u) {
    bf16x8 a[2];
    LDSA(sH, u * 32 + kgrp * 8, a);
    const short* nxt = (u < 3) ? (W2 + (u + 1) * 4096) : nullptr;
    STEP(u & 1, nxt, a);
  }
  {
    float b2c[4], w3v[4][4];
#pragma unroll
    for (int nf = 0; nf < 4; ++nf) {
      int col = wcol + nf * 16 + lrow;
      b2c[nf] = b2[col];
#pragma unroll
      for (int h = 0; h < 4; ++h) w3v[h][nf] = bf2f((u16)W3b[h * 128 + col]);
    }
#pragma unroll
    for (int mi = 0; mi < 2; ++mi)
#pragma unroll
      for (int q = 0; q < 4; ++q) {
        float p0 = 0.f, p1 = 0.f, p2 = 0.f, p3 = 0.f;
#pragma unroll
        for (int nf = 0; nf < 4; ++nf) {
          float x = fmaxf(acc[mi][nf][q] + b2c[nf], 0.f);
          p0 += x * w3v[0][nf]; p1 += x * w3v[1][nf];
          p2 += x * w3v[2][nf]; p3 += x * w3v[3][nf];
        }
#pragma unroll
        for (int o = 1; o < 16; o <<= 1) {
          p0 += __shfl_xor(p0, o); p1 += __shfl_xor(p1, o);
          p2 += __shfl_xor(p2, o); p3 += __shfl_xor(p3, o);
        }
        if (lrow < 4) {
          float pw = (lrow == 0) ? p0 : (lrow == 1) ? p1 : (lrow == 2) ? p2 : p3;
          sPart[wrow + mi * 16 + kgrp * 4 + q][lrow][wid & 1] = pw;
        }
      }
  }
  __syncthreads();
  if (t < 64) {
    int e = eBase + t;
    if (e < E) {
      float4 lg;
      lg.x = (sPart[t][0][0] + sPart[t][0][1] + b3[0]) * 0.17677669529663687f;
      lg.y = (sPart[t][1][0] + sPart[t][1][1] + b3[1]) * 0.17677669529663687f;
      lg.z = (sPart[t][2][0] + sPart[t][2][1] + b3[2]) * 0.17677669529663687f;
      lg.w = (sPart[t][3][0] + sPart[t][3][1] + b3[3]) * 0.17677669529663687f;
      *(float4*)(logits + (size_t)e * 4) = lg;
    }
  }
}

// ---------------- node kernels (order-indirected) ----------------
__global__ void __launch_bounds__(256)
nm_kernel(const float* __restrict__ logits, const int* __restrict__ offs,
          const int* __restrict__ order, float* __restrict__ attw,
          float* __restrict__ inv, int nN) {
  const int wid = threadIdx.x >> 6, lane = threadIdx.x & 63;
  const int nW = gridDim.x * 4;
  for (int v = blockIdx.x * 4 + wid; v < nN; v += nW) {
    const int base = offs[v];
    const int deg = offs[v + 1] - base;
    float m0 = -3e38f, m1 = -3e38f, m2 = -3e38f, m3 = -3e38f;
    for (int i = lane; i < deg; i += 64) {
      int e = order[base + i];
      float4 l = *(const float4*)(logits + (size_t)e * 4);
      m0 = fmaxf(m0, l.x); m1 = fmaxf(m1, l.y);
      m2 = fmaxf(m2, l.z); m3 = fmaxf(m3, l.w);
    }
#pragma unroll
    for (int o = 32; o > 0; o >>= 1) {
      m0 = fmaxf(m0, __shfl_xor(m0, o)); m1 = fmaxf(m1, __shfl_xor(m1, o));
      m2 = fmaxf(m2, __shfl_xor(m2, o)); m3 = fmaxf(m3, __shfl_xor(m3, o));
    }
    float d0 = 0.f, d1 = 0.f, d2 = 0.f, d3 = 0.f;
    for (int i = lane; i < deg; i += 64) {
      int e = order[base + i];
      float4 l = *(const float4*)(logits + (size_t)e * 4);
      float4 ex;
      ex.x = __expf(l.x - m0); ex.y = __expf(l.y - m1);
      ex.z = __expf(l.z - m2); ex.w = __expf(l.w - m3);
      *(float4*)(attw + (size_t)e * 4) = ex;
      d0 += ex.x; d1 += ex.y; d2 += ex.z; d3 += ex.w;
    }
#pragma unroll
    for (int o = 32; o > 0; o >>= 1) {
      d0 += __shfl_xor(d0, o); d1 += __shfl_xor(d1, o);
      d2 += __shfl_xor(d2, o); d3 += __shfl_xor(d3, o);
    }
    if (lane < 4) {
      float dv = (lane == 0) ? d0 : (lane == 1) ? d1 : (lane == 2) ? d2 : d3;
      inv[(size_t)v * 4 + lane] = (dv > 0.f) ? 1.f / dv : 0.f;
    }
  }
}

__device__ __forceinline__ float dot8(const float* ag, uint4 w) {
  unsigned wr[4] = {w.x, w.y, w.z, w.w};
  float s = 0.f;
#pragma unroll
  for (int q = 0; q < 4; ++q) {
    s += ag[2 * q]     * bf2f((u16)(wr[q] & 0xffffu));
    s += ag[2 * q + 1] * bf2f((u16)(wr[q] >> 16));
  }
  return s;
}

// one node per WAVE; lane = 16 dim-groups x 4 edge-slots (16B V loads);
// Wo/Wg cached in LDS (XOR-swizzled); grid-stride over nodes.
__global__ void __launch_bounds__(256, 2)
agg_kernel(const float* __restrict__ hV, const float* __restrict__ attw,
           const float* __restrict__ inv, const u16* __restrict__ V,
           const int* __restrict__ offs, const int* __restrict__ order,
           const short* __restrict__ Wob, const short* __restrict__ Wgb,
           const float* __restrict__ gb, float* __restrict__ out, int nN) {
  __shared__ u16 sW[2][16384];      // 64KB
  __shared__ float sAgg[4][132];
  const int t = threadIdx.x;
#pragma unroll
  for (int i = 0; i < 8; ++i) {
    int idx = t + i * 256;          // 0..2047 uint4 per matrix
    int row = idx >> 4, k16 = idx & 15;
    int di = row * 128 + ((k16 ^ (row & 15)) * 8);
    *(uint4*)&sW[0][di] = ((const uint4*)Wob)[idx];
    *(uint4*)&sW[1][di] = ((const uint4*)Wgb)[idx];
  }
  __syncthreads();
  const int wid = t >> 6, lane = t & 63;
  const int dgrp = lane & 15, egrp = lane >> 4, h = dgrp >> 2;
  const int j0 = lane, j1 = lane + 64;
  const int s0 = (j0 & 15), s1 = (j1 & 15);
  for (int v = blockIdx.x * 4 + wid; v < nN; v += gridDim.x * 4) {
    const int base = offs[v], deg = offs[v + 1] - base;
    float a[8];
#pragma unroll
    for (int q = 0; q < 8; ++q) a[q] = 0.f;
    for (int i = egrp; i < deg; i += 4) {
      int e = order[base + i];
      float w = attw[(size_t)e * 4 + h];
      bf16x8 vv = *(const bf16x8*)(V + (size_t)e * 128 + dgrp * 8);
#pragma unroll
      for (int q = 0; q < 8; ++q) a[q] += w * bf2f((u16)vv[q]);
    }
#pragma unroll
    for (int q = 0; q < 8; ++q) {
      a[q] += __shfl_xor(a[q], 16);
      a[q] += __shfl_xor(a[q], 32);
    }
    if (egrp == 0) {
      float innv = inv[(size_t)v * 4 + h];
#pragma unroll
      for (int q = 0; q < 8; ++q) sAgg[wid][dgrp * 8 + q] = a[q] * innv;
    }
    asm volatile("s_waitcnt lgkmcnt(0)" ::: "memory");
    __builtin_amdgcn_wave_barrier();
    float o0 = 0.f, o1 = 0.f, g0 = 0.f, g1 = 0.f;
#pragma unroll 4
    for (int k = 0; k < 128; k += 8) {
      float a8[8];
#pragma unroll
      for (int q = 0; q < 8; ++q) a8[q] = sAgg[wid][k + q];
      int k16 = k >> 3;
      uint4 wo0 = *(const uint4*)&sW[0][j0 * 128 + ((k16 ^ s0) * 8)];
      uint4 wo1 = *(const uint4*)&sW[0][j1 * 128 + ((k16 ^ s1) * 8)];
      uint4 wg0 = *(const uint4*)&sW[1][j0 * 128 + ((k16 ^ s0) * 8)];
      uint4 wg1 = *(const uint4*)&sW[1][j1 * 128 + ((k16 ^ s1) * 8)];
      o0 += dot8(a8, wo0); o1 += dot8(a8, wo1);
      g0 += dot8(a8, wg0); g1 += dot8(a8, wg1);
    }
    float gg0 = 1.f / (1.f + __expf(-(g0 + gb[j0])));
    float gg1 = 1.f / (1.f + __expf(-(g1 + gb[j1])));
    out[(size_t)v * 128 + j0] = hV[(size_t)v * 128 + j0] + o0 * gg0;
    out[(size_t)v * 128 + j1] = hV[(size_t)v * 128 + j1] + o1 * gg1;
    asm volatile("s_waitcnt lgkmcnt(0)" ::: "memory");
    __builtin_amdgcn_wave_barrier();
  }
}

// ---------------- fallback (ws too small marker) ----------------
__global__ void fb_kernel(const float* __restrict__ hV, float* __restrict__ out, int n) {
  int i = blockIdx.x * 256 + threadIdx.x;
  if (i < n) out[i] = hV[i] + 0.5f;
}

extern "C" void kernel_launch(void* const* d_in, const int* in_sizes, int n_in,
                              void* d_out, int out_size, void* d_ws, size_t ws_size,
                              hipStream_t stream) {
  const float* hV   = (const float*)d_in[0];
  const float* hE   = (const float*)d_in[1];
  const void*  eidx = d_in[2];
  const float* WvW  = (const float*)d_in[3];
  const float* WvB  = (const float*)d_in[4];
  const float* B1w  = (const float*)d_in[5];
  const float* B1b  = (const float*)d_in[6];
  const float* B2w  = (const float*)d_in[7];
  const float* B2b  = (const float*)d_in[8];
  const float* B3w  = (const float*)d_in[9];
  const float* B3b  = (const float*)d_in[10];
  const float* WoW  = (const float*)d_in[11];
  const float* GW   = (const float*)d_in[12];
  const float* GB   = (const float*)d_in[13];

  const int Nn = in_sizes[0] / 128;
  const int E  = in_sizes[1] / 128;
  if (Nn <= 0 || E <= 0) return;

  char* ws = (char*)d_ws;
  size_t off = 0;
  auto alloc = [&](size_t b) { size_t o = off; off += (b + 255) & ~(size_t)255; return o; };
  const size_t o_idx   = alloc((size_t)2 * E * 4);
  const size_t o_cnt   = alloc((size_t)(Nn + 1) * 4);
  const size_t o_offs  = alloc((size_t)(Nn + 1) * 4);
  const size_t o_cur   = alloc((size_t)Nn * 4);
  const size_t o_order = alloc((size_t)E * 4);
  const size_t o_flag  = alloc(256);
  const size_t o_log   = alloc((size_t)E * 16);
  const size_t o_attw  = alloc((size_t)E * 16);
  const size_t o_inv   = alloc((size_t)Nn * 16);
  const size_t o_V     = alloc((size_t)E * 256);
  const size_t o_hVb   = alloc((size_t)Nn * 256);
  const size_t o_wbf   = alloc((size_t)115200 * 2);

  if (off > ws_size) {
    fb_kernel<<<(out_size + 255) / 256, 256, 0, stream>>>(hV, (float*)d_out, out_size);
    return;
  }

  int*   idx32  = (int*)(ws + o_idx);
  int*   cnt    = (int*)(ws + o_cnt);
  int*   offsP  = (int*)(ws + o_offs);
  int*   cur    = (int*)(ws + o_cur);
  int*   order  = (int*)(ws + o_order);
  int*   flag   = (int*)(ws + o_flag);
  float* logits = (float*)(ws + o_log);
  float* attw   = (float*)(ws + o_attw);
  float* invd   = (float*)(ws + o_inv);
  u16*   Vb     = (u16*)(ws + o_V);
  u16*   hVb    = (u16*)(ws + o_hVb);
  short* wbf    = (short*)(ws + o_wbf);

  short* W1b = wbf;
  short* W2b = wbf + 49152;
  short* W3b = wbf + 65536;
  short* Wvb = wbf + 66048;
  short* Wob = wbf + 82432;
  short* Wgb = wbf + 98816;

  const int* src = idx32;
  const int* dst = idx32 + E;

  detect_kernel<<<1, 256, 0, stream>>>((const unsigned*)eidx, flag);
  hipMemsetAsync(cnt, 0, (size_t)(Nn + 1) * 4, stream);
  hipMemsetAsync(cur, 0, (size_t)Nn * 4, stream);
  convert_count_kernel<<<(2 * E + 255) / 256, 256, 0, stream>>>(eidx, idx32, flag, cnt, E);
  scan_kernel<<<1, 1024, 0, stream>>>(cnt, offsP, Nn);
  scatter_kernel<<<(E + 255) / 256, 256, 0, stream>>>(src, offsP, cur, order, E);
  wcvt_kernel<<<(115200 + 255) / 256, 256, 0, stream>>>(B1w, B2w, B3w, WvW, WoW, GW, wbf);
  cvtbf_kernel<<<512, 256, 0, stream>>>(hV, hVb, (long)Nn * 16);

  edge_kernel<<<(E + 63) / 64, 256, 0, stream>>>(
      hVb, hE, src, dst, Vb, W1b, B1b, W2b, B2b, W3b, B3b, Wvb, WvB, logits, E);

  nm_kernel<<<2048, 256, 0, stream>>>(logits, offsP, order, attw, invd, Nn);

  agg_kernel<<<512, 256, 0, stream>>>(
      hV, attw, invd, Vb, offsP, order, Wob, Wgb, GB, (float*)d_out, Nn);
}